// Round 8
// baseline (431.792 us; speedup 1.0000x reference)
//
#include <hip/hip_runtime.h>

// SpatialEvoProp — R8: R7 core + bf16 feat gather table + work-stealing.
// R7 showed the gather path pinned at ~3 TB/s effective with all scheduling
// levers exhausted (compiler sinks batched loads; VGPR pinned 84). Attack
// bytes instead: feat pre-converted to bf16 in d_ws (6.4 MB) -> per-row
// gather 256->128 B, distinct 64B lines per load instruction 32->16 (fully
// consumed), L2 hit rate up. Precision budget: feat quant adds ~5e-3 absmax
// on top of 3.9e-3 (threshold 36.7e-3). Work-stealing batch=2 removes the
// 8.14-groups/stream tail (~9%). ws_size-guarded fallback = exact R7 path.

#define DFEAT 64
#define PPAD 68  // sP row stride (floats)

typedef __attribute__((ext_vector_type(8))) short short8;
typedef __attribute__((ext_vector_type(4))) float floatx4;

__device__ __forceinline__ short bf16h(float x) {
    unsigned u = __float_as_uint(x);
    return (short)((u + 0x7FFFu + ((u >> 16) & 1u)) >> 16);
}
__device__ __forceinline__ float bf16tof(short h) {
    return __uint_as_float(((unsigned)(unsigned short)h) << 16);
}
__device__ __forceinline__ void split8(const float* xs, short8& h, short8& l) {
#pragma unroll
    for (int j = 0; j < 8; ++j) {
        short hh = bf16h(xs[j]);
        h[j] = hh;
        l[j] = bf16h(xs[j] - bf16tof(hh));
    }
}

// count(boundaries < x): analytic seed + shuffle-verified walk against the
// real table values (lane L holds boundaries[L]); exact (verified R3).
__device__ __forceinline__ int bucketize(float x, float bnd) {
    int i = (int)(x * 31.5f);
    i = min(max(i, 0), 64);
#pragma unroll
    for (int t = 0; t < 3; ++t) {
        float bi = __shfl(bnd, min(i, 63));
        if (i < 64 && bi < x) ++i;
    }
#pragma unroll
    for (int t = 0; t < 2; ++t) {
        float bim = __shfl(bnd, max(i - 1, 0));
        if (i > 0 && bim >= x) --i;
    }
    return i;
}

__global__ void k_zero(const float* __restrict__ feat,
                       unsigned short* __restrict__ featb,
                       float* __restrict__ rst, float* __restrict__ degs,
                       int* __restrict__ ctr, int nRst4, int nDeg, int nF4) {
    int i = blockIdx.x * blockDim.x + threadIdx.x;
    if (i < nRst4) ((floatx4*)rst)[i] = (floatx4){0.f, 0.f, 0.f, 0.f};
    if (i < nDeg) degs[i] = 0.0f;
    if (i == 0) *ctr = 0;
    if (i < nF4) {
        floatx4 v = ((const floatx4*)feat)[i];
        unsigned a = ((unsigned)(unsigned short)bf16h(v.x)) |
                     (((unsigned)(unsigned short)bf16h(v.y)) << 16);
        unsigned b = ((unsigned)(unsigned short)bf16h(v.z)) |
                     (((unsigned)(unsigned short)bf16h(v.w)) << 16);
        ((uint2*)featb)[i] = make_uint2(a, b);
    }
}

__global__ void k_deg(const int* __restrict__ src, const int* __restrict__ dst,
                      float* __restrict__ degs, int N, int E) {
    int i = blockIdx.x * blockDim.x + threadIdx.x;
    if (i < E) {
        atomicAdd(&degs[dst[i]], 1.0f);
        atomicAdd(&degs[N + src[i]], 1.0f);
    }
}

template <bool BF16>
__global__ __attribute__((amdgpu_flat_work_group_size(256, 256),
                          amdgpu_waves_per_eu(3, 3))) void k_edge(
    const float* __restrict__ feat, const unsigned short* __restrict__ featb,
    const float* __restrict__ loc, const float* __restrict__ Etab,
    const float* __restrict__ G, const float* __restrict__ agg_w,
    const float* __restrict__ agg_b, const float* __restrict__ bnds,
    const int* __restrict__ src, const int* __restrict__ dst,
    const int* __restrict__ inter, const float* __restrict__ degs,
    int* __restrict__ ctr, float* __restrict__ rst, int N, int E) {
    const int tid = threadIdx.x;
    const int lane = tid & 63;
    const int wid = tid >> 6;
    const int m16 = lane & 15;
    const int quad = lane >> 4;

    __shared__ alignas(16) float sP[65 * PPAD];  // 17680 B
    __shared__ short8 sWBh[16 * 64];             // 16384 B
    __shared__ short8 sWBl[16 * 64];             // 16384 B

    // per-block P = embed @ G_w.T (520 fma/lane, once)
    for (int i = tid; i < 65 * DFEAT; i += 256) {
        int b = i >> 6, o = i & 63;
        float a = 0.0f;
#pragma unroll
        for (int m = 0; m < 32; ++m)
            a = fmaf(Etab[b * 32 + m], G[o * 32 + m], a);
        sP[b * PPAD + o] = a;
    }

    // B-frag f = slab*4+ntile; lane holds n = nt*16+m16, k = sl*32+quad*8+j
    for (int f = wid; f < 16; f += 4) {
        int sl = f >> 2, nt = f & 3;
        const float* wp = agg_w + (nt * 16 + m16) * 128 + sl * 32 + quad * 8;
        float xs[8];
#pragma unroll
        for (int j = 0; j < 8; ++j) xs[j] = wp[j];
        short8 h, l;
        split8(xs, h, l);
        sWBh[f * 64 + lane] = h;
        sWBl[f * 64 + lane] = l;
    }

    const float bnd = bnds[lane];
    float bias4[4];
#pragma unroll
    for (int nt = 0; nt < 4; ++nt) bias4[nt] = agg_b[nt * 16 + m16];

    __syncthreads();

    const int ngroups = (E + 15) >> 4;
    const int o0 = quad * 8;       // slab0 elem offset for this lane
    const int o1 = 32 + quad * 8;  // slab1 elem offset

    while (true) {
        int base;
        if (lane == 0) base = atomicAdd(ctr, 2);  // claim 2 groups
        base = __shfl(base, 0);
        if (base >= ngroups) break;
        const int ge = min(base + 2, ngroups);

        for (int g = base; g < ge; ++g) {
            const int em = (g << 4) + m16;
            const bool act = em < E;
            const int ec = act ? em : 0;

            // -- epoch 1: indices ------------------------------------------
            const int s = src[ec];
            const int d = dst[ec];
            int ij[5];
#pragma unroll
            for (int j = 0; j < 5; ++j) ij[j] = inter[ec * 5 + j];

            // -- epoch 2: loc + degs + feature-row slabs -------------------
            const float2 ls = ((const float2*)loc)[s];
            const float2 ld = ((const float2*)loc)[d];
            float2 lj[5];
#pragma unroll
            for (int j = 0; j < 5; ++j) lj[j] = ((const float2*)loc)[ij[j]];
            float dsc = rsqrtf(fmaxf(degs[d], 1.0f)) *
                        rsqrtf(fmaxf(degs[N + s], 1.0f));
            if (!act) dsc = 0.0f;

            short8 FB[12];   // bf16 path: [row][slab], row0=src, 1..5=inter
            floatx4 F[24];   // f32 fallback path
            if constexpr (BF16) {
                const unsigned short* f0 = featb + (s << 6);
                FB[0] = *(const short8*)(f0 + o0);
                FB[1] = *(const short8*)(f0 + o1);
#pragma unroll
                for (int j = 0; j < 5; ++j) {
                    const unsigned short* fj = featb + (ij[j] << 6);
                    FB[2 + 2 * j] = *(const short8*)(fj + o0);
                    FB[3 + 2 * j] = *(const short8*)(fj + o1);
                }
            } else {
                const float* fr = feat + (s << 6);
                F[0] = *(const floatx4*)(fr + o0);
                F[1] = *(const floatx4*)(fr + o0 + 4);
                F[2] = *(const floatx4*)(fr + o1);
                F[3] = *(const floatx4*)(fr + o1 + 4);
#pragma unroll
                for (int j = 0; j < 5; ++j) {
                    const float* fj = feat + (ij[j] << 6);
                    F[4 + 4 * j + 0] = *(const floatx4*)(fj + o0);
                    F[4 + 4 * j + 1] = *(const floatx4*)(fj + o0 + 4);
                    F[4 + 4 * j + 2] = *(const floatx4*)(fj + o1);
                    F[4 + 4 * j + 3] = *(const floatx4*)(fj + o1 + 4);
                }
            }

            // -- bucketize (pure shuffles; overlaps load latency) ----------
            float dx = ld.x - ls.x, dy = ld.y - ls.y;
            const int b1 = bucketize(sqrtf(dx * dx + dy * dy), bnd);
            int bj[5];
#pragma unroll
            for (int j = 0; j < 5; ++j) {
                float ex = ls.x - lj[j].x, ey = ls.y - lj[j].y;
                bj[j] = bucketize(sqrtf(ex * ex + ey * ey), bnd);
            }

            // -- A fragments: products vs LDS-resident sP ------------------
            short8 Ah[4], Al[4];
#pragma unroll
            for (int sl = 0; sl < 2; ++sl) {  // u: cat[k<64]
                const float* pp = sP + b1 * PPAD + (sl ? o1 : o0);
                floatx4 pa = *(const floatx4*)pp;
                floatx4 pb = *(const floatx4*)(pp + 4);
                float xs[8];
                if constexpr (BF16) {
                    const short8 fs = FB[sl];
                    xs[0] = bf16tof(fs[0]) * pa.x;
                    xs[1] = bf16tof(fs[1]) * pa.y;
                    xs[2] = bf16tof(fs[2]) * pa.z;
                    xs[3] = bf16tof(fs[3]) * pa.w;
                    xs[4] = bf16tof(fs[4]) * pb.x;
                    xs[5] = bf16tof(fs[5]) * pb.y;
                    xs[6] = bf16tof(fs[6]) * pb.z;
                    xs[7] = bf16tof(fs[7]) * pb.w;
                } else {
                    const floatx4 fa = F[2 * sl];
                    const floatx4 fb = F[2 * sl + 1];
                    xs[0] = fa.x * pa.x; xs[1] = fa.y * pa.y;
                    xs[2] = fa.z * pa.z; xs[3] = fa.w * pa.w;
                    xs[4] = fb.x * pb.x; xs[5] = fb.y * pb.y;
                    xs[6] = fb.z * pb.z; xs[7] = fb.w * pb.w;
                }
                split8(xs, Ah[sl], Al[sl]);
            }
#pragma unroll
            for (int sl = 0; sl < 2; ++sl) {  // v: cat[k>=64]
                float r[8] = {0, 0, 0, 0, 0, 0, 0, 0};
#pragma unroll
                for (int j = 0; j < 5; ++j) {
                    const float* pp = sP + bj[j] * PPAD + (sl ? o1 : o0);
                    floatx4 pa = *(const floatx4*)pp;
                    floatx4 pb = *(const floatx4*)(pp + 4);
                    if constexpr (BF16) {
                        const short8 fs = FB[2 + 2 * j + sl];
                        r[0] = fmaf(bf16tof(fs[0]), pa.x, r[0]);
                        r[1] = fmaf(bf16tof(fs[1]), pa.y, r[1]);
                        r[2] = fmaf(bf16tof(fs[2]), pa.z, r[2]);
                        r[3] = fmaf(bf16tof(fs[3]), pa.w, r[3]);
                        r[4] = fmaf(bf16tof(fs[4]), pb.x, r[4]);
                        r[5] = fmaf(bf16tof(fs[5]), pb.y, r[5]);
                        r[6] = fmaf(bf16tof(fs[6]), pb.z, r[6]);
                        r[7] = fmaf(bf16tof(fs[7]), pb.w, r[7]);
                    } else {
                        const floatx4 fa = F[4 + 4 * j + 2 * sl];
                        const floatx4 fb = F[4 + 4 * j + 2 * sl + 1];
                        r[0] = fmaf(fa.x, pa.x, r[0]);
                        r[1] = fmaf(fa.y, pa.y, r[1]);
                        r[2] = fmaf(fa.z, pa.z, r[2]);
                        r[3] = fmaf(fa.w, pa.w, r[3]);
                        r[4] = fmaf(fb.x, pb.x, r[4]);
                        r[5] = fmaf(fb.y, pb.y, r[5]);
                        r[6] = fmaf(fb.z, pb.z, r[6]);
                        r[7] = fmaf(fb.w, pb.w, r[7]);
                    }
                }
                float xs[8];
#pragma unroll
                for (int j = 0; j < 8; ++j) xs[j] = r[j] * 0.2f;
                split8(xs, Ah[2 + sl], Al[2 + sl]);
            }

            // -- MFMA: 4 k-slabs x 4 n-tiles x 3 products ------------------
            floatx4 acc[4] = {
                {0, 0, 0, 0}, {0, 0, 0, 0}, {0, 0, 0, 0}, {0, 0, 0, 0}};
#pragma unroll
            for (int sl = 0; sl < 4; ++sl) {
#pragma unroll
                for (int nt = 0; nt < 4; ++nt) {
                    short8 bh = sWBh[((sl << 2) + nt) * 64 + lane];
                    short8 bl = sWBl[((sl << 2) + nt) * 64 + lane];
                    acc[nt] = __builtin_amdgcn_mfma_f32_16x16x32_bf16(
                        Ah[sl], bh, acc[nt], 0, 0, 0);
                    acc[nt] = __builtin_amdgcn_mfma_f32_16x16x32_bf16(
                        Al[sl], bh, acc[nt], 0, 0, 0);
                    acc[nt] = __builtin_amdgcn_mfma_f32_16x16x32_bf16(
                        Ah[sl], bl, acc[nt], 0, 0, 0);
                }
            }

            // -- epilogue: C row=quad*4+r (edge), col=nt*16+m16 (feature) --
#pragma unroll
            for (int r = 0; r < 4; ++r) {
                const int m = (quad << 2) + r;
                const int dm = __shfl(d, m);
                const float sc = __shfl(dsc, m);
#pragma unroll
                for (int nt = 0; nt < 4; ++nt) {
                    float val = (acc[nt][r] + bias4[nt]) * sc;
                    atomicAdd(&rst[(dm << 6) + nt * 16 + m16], val);
                }
            }
        }
    }
}

extern "C" void kernel_launch(void* const* d_in, const int* in_sizes, int n_in,
                              void* d_out, int out_size, void* d_ws,
                              size_t ws_size, hipStream_t stream) {
    const float* feat  = (const float*)d_in[0];
    const float* loc   = (const float*)d_in[1];
    const float* embed = (const float*)d_in[2];
    const float* G_w   = (const float*)d_in[3];
    const float* agg_w = (const float*)d_in[4];
    const float* agg_b = (const float*)d_in[5];
    const float* bnds  = (const float*)d_in[6];
    const int* src   = (const int*)d_in[7];
    const int* dst   = (const int*)d_in[8];
    const int* inter = (const int*)d_in[9];

    const int N = in_sizes[0] / DFEAT;
    const int E = in_sizes[7];

    float* rst = (float*)d_out;
    char* ws = (char*)d_ws;
    // ws layout: [ctr pad16][degs 2N f32][featb N*64 bf16]
    int* ctr = (int*)ws;
    float* degs = (float*)(ws + 16);
    unsigned short* featb =
        (unsigned short*)(ws + 16 + (size_t)2 * N * sizeof(float));
    const size_t need =
        16 + (size_t)2 * N * sizeof(float) + (size_t)N * DFEAT * 2;
    const bool bf16ok = ws_size >= need;

    const int nRst4 = N * DFEAT / 4;
    const int nDeg = 2 * N;
    const int nF4 = bf16ok ? N * DFEAT / 4 : 0;

    k_zero<<<(nRst4 + 255) / 256, 256, 0, stream>>>(feat, featb, rst, degs,
                                                    ctr, nRst4, nDeg, nF4);
    k_deg<<<(E + 255) / 256, 256, 0, stream>>>(src, dst, degs, N, E);
    if (bf16ok)
        k_edge<true><<<768, 256, 0, stream>>>(feat, featb, loc, embed, G_w,
                                              agg_w, agg_b, bnds, src, dst,
                                              inter, degs, ctr, rst, N, E);
    else
        k_edge<false><<<768, 256, 0, stream>>>(feat, featb, loc, embed, G_w,
                                               agg_w, agg_b, bnds, src, dst,
                                               inter, degs, ctr, rst, N, E);
}